// Round 8
// baseline (157.996 us; speedup 1.0000x reference)
//
#include <hip/hip_runtime.h>

// Problem constants (fixed by reference setup_inputs)
#define BB 32
#define DD 64
#define HH 16
#define TT 256
#define KK 512
#define NN (BB*HH*TT)          // 131072 tokens
#define HT (HH*TT)             // 4096
#define DHT (DD*HT)            // 262144
#define ZQ_SIZE (BB*DD*HH*TT)
#define COMMIT_OFF ZQ_SIZE
#define IDX_OFF (ZQ_SIZE+1)
#define PPL_OFF (IDX_OFF+NN)
#define USE_OFF (PPL_OFF+1)

// ws layout (float offsets):
#define CNT_OFF    0       // counts[512]
#define CPART_OFF  512     // per-block commit partials[512]
#define TICKET_OFF 1024    // int ticket for last-block stats
#define EBH_OFF    1088    // 512x64 bf16 hi = 16384 floats
#define EBL_OFF    17472   // 512x64 bf16 lo = 16384 floats

// rescue margin on the DOT scale: covers split-bf16 err (~3e-4) + pack quantum (~5e-4 x2)
#define MARGIN_A 1.5e-3f

using bf16x8 = __attribute__((ext_vector_type(8))) short;
using f32x4  = __attribute__((ext_vector_type(4))) float;

__device__ __forceinline__ unsigned bf16_rne(float x) {
    unsigned u = __float_as_uint(x);
    return (u + 0x7FFFu + ((u >> 16) & 1u)) >> 16;   // bf16 bits in low 16
}
__device__ __forceinline__ bf16x8 bc(uint4 v) { return __builtin_bit_cast(bf16x8, v); }

// 32 blocks x 256: split-bf16 embedding; block 0 zeroes counts + ticket + rescue count.
__global__ void vq_init(const float* __restrict__ emb, float* __restrict__ ws,
                        float* __restrict__ zq_scratch) {
    const int tid = threadIdx.x, blk = blockIdx.x;
    if (blk == 0) {
        ws[CNT_OFF + tid] = 0.0f;
        ws[CNT_OFF + 256 + tid] = 0.0f;
        if (tid == 0) { ((int*)(ws + TICKET_OFF))[0] = 0; ((int*)zq_scratch)[0] = 0; }
    }
    const int k  = blk * 16 + (tid >> 4);
    const int d0 = (tid & 15) * 4;
    float4 v = *reinterpret_cast<const float4*>(emb + k * DD + d0);
    unsigned hx = bf16_rne(v.x), hy = bf16_rne(v.y), hz = bf16_rne(v.z), hw = bf16_rne(v.w);
    float lx = v.x - __uint_as_float(hx << 16);
    float ly = v.y - __uint_as_float(hy << 16);
    float lz = v.z - __uint_as_float(hz << 16);
    float lw = v.w - __uint_as_float(hw << 16);
    uint2 hi, lo;
    hi.x = hx | (hy << 16);            hi.y = hz | (hw << 16);
    lo.x = bf16_rne(lx) | (bf16_rne(ly) << 16);
    lo.y = bf16_rne(lz) | (bf16_rne(lw) << 16);
    reinterpret_cast<uint2*>(ws + EBH_OFF)[(k * DD + d0) >> 2] = hi;
    reinterpret_cast<uint2*>(ws + EBL_OFF)[(k * DD + d0) >> 2] = lo;
}

// Screen: 64 tokens/wave x 512 codes, split-bf16 MFMA, 2 LDS phases of 256 codes.
// Latency fixes vs r7: dual 3-deep MFMA chains per tile (8 indep chains/ctl),
// min-tracking deferred one iteration (psum), med3 top-2 update (3 VALU/elem).
__global__ __launch_bounds__(256, 2) void vq_screen(
    const float* __restrict__ z_e, const float* __restrict__ ws,
    float* __restrict__ out_idx, float* __restrict__ zq_scratch)
{
    __shared__ uint4 sh[2][2304];   // [hi/lo][256 codes * 9] = 73728 B

    const int tid  = threadIdx.x;
    const int lane = tid & 63;
    const int col  = lane & 15;
    const int q    = lane >> 4;
    const int W    = (blockIdx.x * 256 + tid) >> 6;   // 0..2047
    const int base_tok = W * 64;

    const uint4* ebh4 = reinterpret_cast<const uint4*>(ws + EBH_OFF);
    const uint4* ebl4 = reinterpret_cast<const uint4*>(ws + EBL_OFF);

    // ---- A fragments: 4 token-tiles x 2 k-frags, hi/lo split ----
    bf16x8 ah[4][2], al[4][2];
#pragma unroll
    for (int s = 0; s < 4; ++s) {
        const int n = base_tok + s * 16 + col;
        const size_t zoff = (size_t)(n >> 12) * DHT + (size_t)((n >> 8) & 15) * 256 + (size_t)(n & 255);
#pragma unroll
        for (int kf = 0; kf < 2; ++kf) {
            const int d0 = kf * 32 + q * 8;
            unsigned hu[4], lu[4];
#pragma unroll
            for (int jj = 0; jj < 4; ++jj) {
                float z0 = z_e[zoff + (size_t)(d0 + 2*jj + 0) * HT];
                float z1 = z_e[zoff + (size_t)(d0 + 2*jj + 1) * HT];
                unsigned h0 = bf16_rne(z0), h1 = bf16_rne(z1);
                float l0 = z0 - __uint_as_float(h0 << 16);
                float l1 = z1 - __uint_as_float(h1 << 16);
                hu[jj] = h0 | (h1 << 16);
                lu[jj] = bf16_rne(l0) | (bf16_rne(l1) << 16);
            }
            ah[s][kf] = bc(make_uint4(hu[0], hu[1], hu[2], hu[3]));
            al[s][kf] = bc(make_uint4(lu[0], lu[1], lu[2], lu[3]));
        }
    }

    // top-2 packed-max state (code id in low 9 mantissa bits)
    float m1[4][4], m2[4][4];
    f32x4 psum[4];   // deferred dots from previous iteration
#pragma unroll
    for (int s = 0; s < 4; ++s) {
        psum[s] = f32x4{-3.4e38f, -3.4e38f, -3.4e38f, -3.4e38f};
#pragma unroll
        for (int r = 0; r < 4; ++r) { m1[s][r] = -3.4e38f; m2[s][r] = -3.4e38f; }
    }

    unsigned ktag = (unsigned)col;   // tag for CURRENT iteration's dots
    unsigned ptag = (unsigned)col;   // tag matching psum

#pragma unroll
    for (int p = 0; p < 2; ++p) {
        if (p) __syncthreads();   // phase-0 reads done before overwrite
        // stage 256 codes (hi+lo): 8 uint4 per array per thread, coalesced
#pragma unroll
        for (int j = 0; j < 8; ++j) {
            const int local = j * 256 + tid;
            const int c = local >> 3, jj = local & 7;
            sh[0][c * 9 + jj] = ebh4[p * 2048 + local];
            sh[1][c * 9 + jj] = ebl4[p * 2048 + local];
        }
        __syncthreads();

#pragma unroll 4
        for (int ctl = 0; ctl < 16; ++ctl) {
            const int row9 = (ctl * 16 + col) * 9;
            bf16x8 bh0 = bc(sh[0][row9 + q]);
            bf16x8 bh1 = bc(sh[0][row9 + 4 + q]);
            bf16x8 bl0 = bc(sh[1][row9 + q]);
            bf16x8 bl1 = bc(sh[1][row9 + 4 + q]);

            f32x4 accA[4], accB[4];
#pragma unroll
            for (int s = 0; s < 4; ++s) {
                f32x4 a = {0.f, 0.f, 0.f, 0.f};
                a = __builtin_amdgcn_mfma_f32_16x16x32_bf16(ah[s][0], bh0, a, 0, 0, 0);
                a = __builtin_amdgcn_mfma_f32_16x16x32_bf16(al[s][0], bh0, a, 0, 0, 0);
                a = __builtin_amdgcn_mfma_f32_16x16x32_bf16(ah[s][0], bl0, a, 0, 0, 0);
                accA[s] = a;
                f32x4 b = {0.f, 0.f, 0.f, 0.f};
                b = __builtin_amdgcn_mfma_f32_16x16x32_bf16(ah[s][1], bh1, b, 0, 0, 0);
                b = __builtin_amdgcn_mfma_f32_16x16x32_bf16(al[s][1], bh1, b, 0, 0, 0);
                b = __builtin_amdgcn_mfma_f32_16x16x32_bf16(ah[s][1], bl1, b, 0, 0, 0);
                accB[s] = b;
            }

            // min-track PREVIOUS iteration's dots (independent of this ctl's MFMAs)
#pragma unroll
            for (int s = 0; s < 4; ++s)
#pragma unroll
                for (int r = 0; r < 4; ++r) {
                    float pk = __uint_as_float((__float_as_uint(psum[s][r]) & 0xFFFFFE00u) | ptag);
                    m2[s][r] = __builtin_amdgcn_fmed3f(pk, m1[s][r], m2[s][r]);
                    m1[s][r] = fmaxf(m1[s][r], pk);
                }

            // merge dual accumulators -> becomes next iteration's psum
#pragma unroll
            for (int s = 0; s < 4; ++s) psum[s] = accA[s] + accB[s];
            ptag = ktag;
            ktag += 16u;
        }
    }
    // final deferred track
#pragma unroll
    for (int s = 0; s < 4; ++s)
#pragma unroll
        for (int r = 0; r < 4; ++r) {
            float pk = __uint_as_float((__float_as_uint(psum[s][r]) & 0xFFFFFE00u) | ptag);
            m2[s][r] = __builtin_amdgcn_fmed3f(pk, m1[s][r], m2[s][r]);
            m1[s][r] = fmaxf(m1[s][r], pk);
        }

    // cross-lane top-2 merge over the 16 cols within each quad group
#pragma unroll
    for (int msk = 1; msk <= 8; msk <<= 1) {
#pragma unroll
        for (int s = 0; s < 4; ++s)
#pragma unroll
            for (int r = 0; r < 4; ++r) {
                float o1 = __shfl_xor(m1[s][r], msk, 64);
                float o2 = __shfl_xor(m2[s][r], msk, 64);
                m2[s][r] = __builtin_amdgcn_fmed3f(m1[s][r], o1, fmaxf(m2[s][r], o2));
                m1[s][r] = fmaxf(m1[s][r], o1);
            }
    }

    if (col == 0) {
        int* rc = (int*)zq_scratch;
        int* rlist = rc + 1;
#pragma unroll
        for (int s = 0; s < 4; ++s)
#pragma unroll
            for (int r = 0; r < 4; ++r) {
                int token = base_tok + s * 16 + q * 4 + r;
                out_idx[token] = (float)(__float_as_uint(m1[s][r]) & 511u);
                if (m1[s][r] - m2[s][r] < MARGIN_A) { int pp = atomicAdd(rc, 1); rlist[pp] = token; }
            }
    }
}

// Rescue: exact fp32 full rescan for ambiguous tokens. Block (512 thr) per token.
__global__ void vq_rescue(const float* __restrict__ z_e, const float* __restrict__ emb,
                          float* __restrict__ out_idx, const float* __restrict__ zq_scratch)
{
    __shared__ float lz[DD];
    __shared__ float sd[512];
    __shared__ int   si[512];
    const int tid = threadIdx.x;
    const int cnt = ((const int*)zq_scratch)[0];
    const int* rlist = ((const int*)zq_scratch) + 1;

    for (int it = blockIdx.x; it < cnt; it += gridDim.x) {
        const int n = rlist[it];
        const int b = n >> 12, h = (n >> 8) & 15, t = n & 255;
        const size_t zoff = (size_t)b * DHT + (size_t)h * 256 + (size_t)t;
        __syncthreads();
        if (tid < DD) lz[tid] = z_e[zoff + (size_t)tid * HT];
        __syncthreads();
        const float4* er = reinterpret_cast<const float4*>(emb + (size_t)tid * DD);
        float a0 = 0.f, a1 = 0.f, a2 = 0.f, a3 = 0.f;
#pragma unroll
        for (int i = 0; i < 16; ++i) {
            float4 e4 = er[i];
            float d0 = lz[4*i+0] - e4.x; a0 = fmaf(d0, d0, a0);
            float d1 = lz[4*i+1] - e4.y; a1 = fmaf(d1, d1, a1);
            float d2 = lz[4*i+2] - e4.z; a2 = fmaf(d2, d2, a2);
            float d3 = lz[4*i+3] - e4.w; a3 = fmaf(d3, d3, a3);
        }
        sd[tid] = (a0 + a1) + (a2 + a3);
        si[tid] = tid;
        __syncthreads();
        for (int off = 256; off > 0; off >>= 1) {
            if (tid < off) {
                float d2 = sd[tid + off]; int j2 = si[tid + off];
                if (d2 < sd[tid] || (d2 == sd[tid] && j2 < si[tid])) { sd[tid] = d2; si[tid] = j2; }
            }
            __syncthreads();
        }
        if (tid == 0) out_idx[n] = (float)si[0];
    }
}

// Finalize: z_q gather/write + commitment partial + histogram + (last block) stats.
__global__ __launch_bounds__(256) void vq_finalize(
    const float* __restrict__ z_e, const float* __restrict__ emb,
    const float* __restrict__ idx_in, float* __restrict__ out_zq,
    float* __restrict__ ws, float* __restrict__ out)
{
    __shared__ float wsum[4];
    __shared__ int hist[KK];
    __shared__ float s_a[KK], s_b[KK];
    __shared__ int s_u[KK];
    __shared__ int islast;

    float* counts = ws + CNT_OFF;
    float* cpart  = ws + CPART_OFF;
    int*   ticket = (int*)(ws + TICKET_OFF);

    const int tid = threadIdx.x;
    hist[tid] = 0; hist[tid + 256] = 0;
    const int n   = blockIdx.x * 256 + tid;
    const int b   = n >> 12;
    const int h   = (n >> 8) & 15;
    const int t   = n & 255;
    const size_t zbase = (size_t)b * DHT + (size_t)h * TT + (size_t)t;

    const int bidx = (int)idx_in[n];
    __syncthreads();
    atomicAdd(&hist[bidx], 1);
    const float4* er = reinterpret_cast<const float4*>(emb + (size_t)bidx * DD);
    float a0 = 0.f, a1 = 0.f, a2 = 0.f, a3 = 0.f;
#pragma unroll
    for (int i = 0; i < 16; ++i) {
        float4 e4 = er[i];
        float z0 = z_e[zbase + (size_t)(4*i+0) * HT];
        float z1 = z_e[zbase + (size_t)(4*i+1) * HT];
        float z2 = z_e[zbase + (size_t)(4*i+2) * HT];
        float z3 = z_e[zbase + (size_t)(4*i+3) * HT];
        out_zq[zbase + (size_t)(4*i+0) * HT] = e4.x;
        out_zq[zbase + (size_t)(4*i+1) * HT] = e4.y;
        out_zq[zbase + (size_t)(4*i+2) * HT] = e4.z;
        out_zq[zbase + (size_t)(4*i+3) * HT] = e4.w;
        float d0 = z0 - e4.x; a0 = fmaf(d0, d0, a0);
        float d1 = z1 - e4.y; a1 = fmaf(d1, d1, a1);
        float d2 = z2 - e4.z; a2 = fmaf(d2, d2, a2);
        float d3 = z3 - e4.w; a3 = fmaf(d3, d3, a3);
    }
    float dmin = (a0 + a1) + (a2 + a3);
#pragma unroll
    for (int off = 32; off > 0; off >>= 1) dmin += __shfl_down(dmin, off, 64);
    if ((tid & 63) == 0) wsum[tid >> 6] = dmin;
    __syncthreads();
    if (tid == 0) cpart[blockIdx.x] = (wsum[0] + wsum[1]) + (wsum[2] + wsum[3]);
    int c = hist[tid];       if (c) atomicAdd(&counts[tid],       (float)c);
    c     = hist[tid + 256]; if (c) atomicAdd(&counts[tid + 256], (float)c);

    // ---- last-block stats (fused vq_stats) ----
    if (tid == 0) {
        __threadfence();
        islast = (atomicAdd(ticket, 1) == (int)gridDim.x - 1) ? 1 : 0;
    }
    __syncthreads();
    if (islast) {
        __threadfence();
#pragma unroll
        for (int k2 = tid; k2 < KK; k2 += 256) {
            float cc = counts[k2];
            float p  = cc * (1.0f / (float)NN);
            s_a[k2] = p * logf(p + 1e-12f);
            s_u[k2] = (p > 0.0f) ? 1 : 0;
            s_b[k2] = cpart[k2];
        }
        __syncthreads();
        for (int off = 256; off > 0; off >>= 1) {
            if (tid < off) {
                s_a[tid] += s_a[tid + off];
                s_u[tid] += s_u[tid + off];
                s_b[tid] += s_b[tid + off];
            }
            __syncthreads();
        }
        if (tid == 0) {
            out[COMMIT_OFF] = 0.25f * s_b[0] / (float)ZQ_SIZE;
            out[PPL_OFF]    = expf(-s_a[0]);
            out[USE_OFF]    = (float)s_u[0] / (float)KK;
        }
    }
}

extern "C" void kernel_launch(void* const* d_in, const int* in_sizes, int n_in,
                              void* d_out, int out_size, void* d_ws, size_t ws_size,
                              hipStream_t stream) {
    const float* z_e = (const float*)d_in[0];
    const float* emb = (const float*)d_in[1];
    float* out = (float*)d_out;
    float* ws  = (float*)d_ws;

    float* out_idx = out + IDX_OFF;
    float* zq_scratch = out;   // z_q region doubles as rescue scratch until finalize

    vq_init<<<32, 256, 0, stream>>>(emb, ws, zq_scratch);
    vq_screen<<<512, 256, 0, stream>>>(z_e, ws, out_idx, zq_scratch);
    vq_rescue<<<256, 512, 0, stream>>>(z_e, emb, out_idx, zq_scratch);
    vq_finalize<<<512, 256, 0, stream>>>(z_e, emb, out_idx, out, ws, out);
}

// Round 9
// 133.447 us; speedup vs baseline: 1.1840x; 1.1840x over previous
//
#include <hip/hip_runtime.h>

// Problem constants (fixed by reference setup_inputs)
#define BB 32
#define DD 64
#define HH 16
#define TT 256
#define KK 512
#define NN (BB*HH*TT)          // 131072 tokens
#define HT (HH*TT)             // 4096
#define DHT (DD*HT)            // 262144
#define ZQ_SIZE (BB*DD*HH*TT)
#define COMMIT_OFF ZQ_SIZE
#define IDX_OFF (ZQ_SIZE+1)
#define PPL_OFF (IDX_OFF+NN)
#define USE_OFF (PPL_OFF+1)

// ws layout (float offsets):
#define CNT_OFF    0       // counts[512]
#define CPART_OFF  512     // per-wave commit partials[2048] (plain stores)
#define CDELTA_OFF 2560    // rescue commitment correction (float atomic)
#define RC_OFF     2561    // int rescue count
#define RLIST_OFF  2562    // (token:int, dminA:float-bits) pairs, up to RMAX
#define RMAX       16384
#define EBH_OFF    36864   // 512x64 bf16 hi = 16384 floats
#define EBL_OFF    53248   // 512x64 bf16 lo = 16384 floats

// rescue margin on the DOT scale: covers split-bf16 err (~3e-4) + pack quantum (~5e-4 x2)
#define MARGIN_A 1.5e-3f

using bf16x8 = __attribute__((ext_vector_type(8))) short;
using f32x4  = __attribute__((ext_vector_type(4))) float;

__device__ __forceinline__ unsigned bf16_rne(float x) {
    unsigned u = __float_as_uint(x);
    return (u + 0x7FFFu + ((u >> 16) & 1u)) >> 16;   // bf16 bits in low 16
}
__device__ __forceinline__ bf16x8 bc(uint4 v) { return __builtin_bit_cast(bf16x8, v); }
__device__ __forceinline__ float pick4(float a0, float a1, float a2, float a3, int i) {
    float x = (i & 1) ? a1 : a0;
    float y = (i & 1) ? a3 : a2;
    return (i & 2) ? y : x;
}

// 32 blocks x 256: split-bf16 embedding; block 0 zeroes counts + cdelta + rc.
__global__ void vq_init(const float* __restrict__ emb, float* __restrict__ ws) {
    const int tid = threadIdx.x, blk = blockIdx.x;
    if (blk == 0) {
        ws[CNT_OFF + tid] = 0.0f;
        ws[CNT_OFF + 256 + tid] = 0.0f;
        if (tid == 0) { ws[CDELTA_OFF] = 0.0f; ((int*)ws)[RC_OFF] = 0; }
    }
    const int k  = blk * 16 + (tid >> 4);
    const int d0 = (tid & 15) * 4;
    float4 v = *reinterpret_cast<const float4*>(emb + k * DD + d0);
    unsigned hx = bf16_rne(v.x), hy = bf16_rne(v.y), hz = bf16_rne(v.z), hw = bf16_rne(v.w);
    float lx = v.x - __uint_as_float(hx << 16);
    float ly = v.y - __uint_as_float(hy << 16);
    float lz = v.z - __uint_as_float(hz << 16);
    float lw = v.w - __uint_as_float(hw << 16);
    uint2 hi, lo;
    hi.x = hx | (hy << 16);            hi.y = hz | (hw << 16);
    lo.x = bf16_rne(lx) | (bf16_rne(ly) << 16);
    lo.y = bf16_rne(lz) | (bf16_rne(lw) << 16);
    reinterpret_cast<uint2*>(ws + EBH_OFF)[(k * DD + d0) >> 2] = hi;
    reinterpret_cast<uint2*>(ws + EBL_OFF)[(k * DD + d0) >> 2] = lo;
}

// Screen: 64 tokens/wave x 512 codes, split-bf16 MFMA, 2 LDS phases of 256 codes,
// register-prefetched B-frags (next ctl's ds_reads issue before this ctl's MFMAs).
// Fused epilogue: idx, z_q gather/write, commit partial, histogram, rescue list.
__global__ __launch_bounds__(256, 2) void vq_screen(
    const float* __restrict__ z_e, const float* __restrict__ emb,
    float* __restrict__ ws, float* __restrict__ out_zq, float* __restrict__ out_idx)
{
    __shared__ uint4 sh[2][2304];   // [hi/lo][256 codes * 9] = 73728 B
    __shared__ int hist[KK];        // + 2 KB

    const int tid  = threadIdx.x;
    const int lane = tid & 63;
    const int col  = lane & 15;
    const int q    = lane >> 4;
    const int W    = (blockIdx.x * 256 + tid) >> 6;   // global wave id, 0..2047
    const int base_tok = W * 64;

    hist[tid] = 0; hist[tid + 256] = 0;

    const uint4* ebh4 = reinterpret_cast<const uint4*>(ws + EBH_OFF);
    const uint4* ebl4 = reinterpret_cast<const uint4*>(ws + EBL_OFF);

    // ---- A fragments: 4 token-tiles x 2 k-frags, hi/lo split; + per-(s) |z|^2 partials
    bf16x8 ah[4][2], al[4][2];
    float zp[4];
#pragma unroll
    for (int s = 0; s < 4; ++s) {
        zp[s] = 0.0f;
        const int n = base_tok + s * 16 + col;
        const size_t zoff = (size_t)(n >> 12) * DHT + (size_t)((n >> 8) & 15) * 256 + (size_t)(n & 255);
#pragma unroll
        for (int kf = 0; kf < 2; ++kf) {
            const int d0 = kf * 32 + q * 8;
            unsigned hu[4], lu[4];
#pragma unroll
            for (int jj = 0; jj < 4; ++jj) {
                float z0 = z_e[zoff + (size_t)(d0 + 2*jj + 0) * HT];
                float z1 = z_e[zoff + (size_t)(d0 + 2*jj + 1) * HT];
                zp[s] = fmaf(z0, z0, zp[s]);
                zp[s] = fmaf(z1, z1, zp[s]);
                unsigned h0 = bf16_rne(z0), h1 = bf16_rne(z1);
                float l0 = z0 - __uint_as_float(h0 << 16);
                float l1 = z1 - __uint_as_float(h1 << 16);
                hu[jj] = h0 | (h1 << 16);
                lu[jj] = bf16_rne(l0) | (bf16_rne(l1) << 16);
            }
            ah[s][kf] = bc(make_uint4(hu[0], hu[1], hu[2], hu[3]));
            al[s][kf] = bc(make_uint4(lu[0], lu[1], lu[2], lu[3]));
        }
    }
    // complete per-token |z|^2 (sum over the 4 q-lanes of each col)
#pragma unroll
    for (int s = 0; s < 4; ++s) {
        zp[s] += __shfl_xor(zp[s], 16, 64);
        zp[s] += __shfl_xor(zp[s], 32, 64);
    }

    // top-2 packed-max state (code id in low 9 mantissa bits)
    float m1[4][4], m2[4][4];
#pragma unroll
    for (int s = 0; s < 4; ++s)
#pragma unroll
        for (int r = 0; r < 4; ++r) { m1[s][r] = -3.4e38f; m2[s][r] = -3.4e38f; }

    unsigned ktag = (unsigned)col;
    const int idx0 = col * 9 + q;   // this lane's uint4 row base within a code-tile

#pragma unroll
    for (int p = 0; p < 2; ++p) {
        if (p) __syncthreads();   // phase-0 reads done before overwrite
#pragma unroll
        for (int j = 0; j < 8; ++j) {
            const int local = j * 256 + tid;
            const int c = local >> 3, jj = local & 7;
            sh[0][c * 9 + jj] = ebh4[p * 2048 + local];
            sh[1][c * 9 + jj] = ebl4[p * 2048 + local];
        }
        __syncthreads();

        // prologue loads for ctl=0
        uint4 nh0 = sh[0][idx0], nh1 = sh[0][idx0 + 4];
        uint4 nl0 = sh[1][idx0], nl1 = sh[1][idx0 + 4];

#pragma unroll 4
        for (int ctl = 0; ctl < 16; ++ctl) {
            bf16x8 bh0 = bc(nh0), bh1 = bc(nh1);
            bf16x8 bl0 = bc(nl0), bl1 = bc(nl1);
            if (ctl < 15) {   // prefetch next ctl BEFORE this ctl's MFMAs
                const int ni = idx0 + (ctl + 1) * 144;
                nh0 = sh[0][ni]; nh1 = sh[0][ni + 4];
                nl0 = sh[1][ni]; nl1 = sh[1][ni + 4];
            }
#pragma unroll
            for (int s = 0; s < 4; ++s) {
                f32x4 acc = {0.f, 0.f, 0.f, 0.f};
                acc = __builtin_amdgcn_mfma_f32_16x16x32_bf16(ah[s][0], bh0, acc, 0, 0, 0);
                acc = __builtin_amdgcn_mfma_f32_16x16x32_bf16(ah[s][1], bh1, acc, 0, 0, 0);
                acc = __builtin_amdgcn_mfma_f32_16x16x32_bf16(al[s][0], bh0, acc, 0, 0, 0);
                acc = __builtin_amdgcn_mfma_f32_16x16x32_bf16(al[s][1], bh1, acc, 0, 0, 0);
                acc = __builtin_amdgcn_mfma_f32_16x16x32_bf16(ah[s][0], bl0, acc, 0, 0, 0);
                acc = __builtin_amdgcn_mfma_f32_16x16x32_bf16(ah[s][1], bl1, acc, 0, 0, 0);
#pragma unroll
                for (int r = 0; r < 4; ++r) {
                    float pk = __uint_as_float((__float_as_uint(acc[r]) & 0xFFFFFE00u) | ktag);
                    m2[s][r] = __builtin_amdgcn_fmed3f(pk, m1[s][r], m2[s][r]);
                    m1[s][r] = fmaxf(m1[s][r], pk);
                }
            }
            ktag += 16u;
        }
    }

    // cross-lane top-2 merge: after this, ALL 16 col-lanes share identical m1/m2
#pragma unroll
    for (int msk = 1; msk <= 8; msk <<= 1) {
#pragma unroll
        for (int s = 0; s < 4; ++s)
#pragma unroll
            for (int r = 0; r < 4; ++r) {
                float o1 = __shfl_xor(m1[s][r], msk, 64);
                float o2 = __shfl_xor(m2[s][r], msk, 64);
                m2[s][r] = __builtin_amdgcn_fmed3f(m1[s][r], o1, fmaxf(m2[s][r], o2));
                m1[s][r] = fmaxf(m1[s][r], o1);
            }
    }

    // ---- per-lane writeout: lane handles token (s0 = col>>2, r0 = col&3, own q) ----
    const int s0 = col >> 2, r0 = col & 3;
    const int token = base_tok + s0 * 16 + q * 4 + r0;

    float m1v, m2v;
    {
        float a = pick4(m1[0][0], m1[0][1], m1[0][2], m1[0][3], r0);
        float b = pick4(m1[1][0], m1[1][1], m1[1][2], m1[1][3], r0);
        float c = pick4(m1[2][0], m1[2][1], m1[2][2], m1[2][3], r0);
        float d = pick4(m1[3][0], m1[3][1], m1[3][2], m1[3][3], r0);
        m1v = pick4(a, b, c, d, s0);
        a = pick4(m2[0][0], m2[0][1], m2[0][2], m2[0][3], r0);
        b = pick4(m2[1][0], m2[1][1], m2[1][2], m2[1][3], r0);
        c = pick4(m2[2][0], m2[2][1], m2[2][2], m2[2][3], r0);
        d = pick4(m2[3][0], m2[3][1], m2[3][2], m2[3][3], s0 * 0 + r0);
        m2v = pick4(a, b, c, d, s0);
    }
    // zsq of my token lives (for index s) on lane col==q*4+r0 (any q there)
    const int c0 = q * 4 + r0;
    float z0s = __shfl(zp[0], c0, 64);
    float z1s = __shfl(zp[1], c0, 64);
    float z2s = __shfl(zp[2], c0, 64);
    float z3s = __shfl(zp[3], c0, 64);
    const float zsqv = pick4(z0s, z1s, z2s, z3s, s0);

    const int k_sel = (int)(__float_as_uint(m1v) & 511u);
    const float dminA = fmaf(-2.0f, m1v, zsqv + 1.0f);   // ||z||^2 + 1 - 2*dot

    out_idx[token] = (float)k_sel;
    if (m1v - m2v < MARGIN_A) {
        int* rc = (int*)ws + RC_OFF;
        int pp = atomicAdd(rc, 1);
        if (pp < RMAX) {
            int* rl = (int*)ws + RLIST_OFF;
            rl[2 * pp] = token;
            rl[2 * pp + 1] = (int)__float_as_uint(dminA);
        }
    }
    atomicAdd(&hist[k_sel], 1);

    // commitment: wave-reduce dminA -> one partial per wave (plain store)
    float csum = dminA;
#pragma unroll
    for (int off = 32; off > 0; off >>= 1) csum += __shfl_down(csum, off, 64);
    if (lane == 0) ws[CPART_OFF + W] = csum;

    // z_q: gather winner row (fp32, L2-hot) and write strided
    {
        const int b = token >> 12, h = (token >> 8) & 15, t = token & 255;
        const size_t zb = (size_t)b * DHT + (size_t)h * TT + (size_t)t;
        const float4* er = reinterpret_cast<const float4*>(emb + (size_t)k_sel * DD);
#pragma unroll
        for (int i = 0; i < 16; ++i) {
            float4 v = er[i];
            out_zq[zb + (size_t)(4*i+0) * HT] = v.x;
            out_zq[zb + (size_t)(4*i+1) * HT] = v.y;
            out_zq[zb + (size_t)(4*i+2) * HT] = v.z;
            out_zq[zb + (size_t)(4*i+3) * HT] = v.w;
        }
    }

    // histogram -> global (low contention: one pass per block)
    __syncthreads();
    int c = hist[tid];       if (c) atomicAdd(ws + CNT_OFF + tid,       (float)c);
    c     = hist[tid + 256]; if (c) atomicAdd(ws + CNT_OFF + tid + 256, (float)c);
}

// Rescue: exact fp32 full rescan for ambiguous tokens; patches idx, z_q, counts, commit.
__global__ void vq_rescue(const float* __restrict__ z_e, const float* __restrict__ emb,
                          float* __restrict__ ws, float* __restrict__ out_zq,
                          float* __restrict__ out_idx)
{
    __shared__ float lz[DD];
    __shared__ float sd[512];
    __shared__ int   si[512];
    const int tid = threadIdx.x;
    int cnt = ((const int*)ws)[RC_OFF];
    if (cnt > RMAX) cnt = RMAX;
    const int* rl = (const int*)ws + RLIST_OFF;

    for (int it = blockIdx.x; it < cnt; it += gridDim.x) {
        const int n = rl[2 * it];
        const float dminA = __uint_as_float((unsigned)rl[2 * it + 1]);
        const int b = n >> 12, h = (n >> 8) & 15, t = n & 255;
        const size_t zoff = (size_t)b * DHT + (size_t)h * 256 + (size_t)t;
        __syncthreads();
        if (tid < DD) lz[tid] = z_e[zoff + (size_t)tid * HT];
        __syncthreads();
        const float4* er = reinterpret_cast<const float4*>(emb + (size_t)tid * DD);
        float a0 = 0.f, a1 = 0.f, a2 = 0.f, a3 = 0.f;
#pragma unroll
        for (int i = 0; i < 16; ++i) {
            float4 e4 = er[i];
            float d0 = lz[4*i+0] - e4.x; a0 = fmaf(d0, d0, a0);
            float d1 = lz[4*i+1] - e4.y; a1 = fmaf(d1, d1, a1);
            float d2 = lz[4*i+2] - e4.z; a2 = fmaf(d2, d2, a2);
            float d3 = lz[4*i+3] - e4.w; a3 = fmaf(d3, d3, a3);
        }
        sd[tid] = (a0 + a1) + (a2 + a3);
        si[tid] = tid;
        __syncthreads();
        for (int off = 256; off > 0; off >>= 1) {
            if (tid < off) {
                float d2 = sd[tid + off]; int j2 = si[tid + off];
                if (d2 < sd[tid] || (d2 == sd[tid] && j2 < si[tid])) { sd[tid] = d2; si[tid] = j2; }
            }
            __syncthreads();
        }
        const int   k_new = si[0];
        const float d_new = sd[0];
        const int   k_old = (int)out_idx[n];
        if (tid == 0) {
            atomicAdd(ws + CDELTA_OFF, d_new - dminA);   // exact commitment correction
            if (k_new != k_old) {
                out_idx[n] = (float)k_new;
                atomicAdd(ws + CNT_OFF + k_old, -1.0f);
                atomicAdd(ws + CNT_OFF + k_new,  1.0f);
            }
        }
        if (k_new != k_old && tid < DD)
            out_zq[zoff + (size_t)tid * HT] = emb[(size_t)k_new * DD + tid];
        __syncthreads();
    }
}

// Stats: 1 block, 512 threads. counts -> entropy/usage; cpart[2048]+cdelta -> commitment.
__global__ void vq_stats(const float* __restrict__ ws, float* __restrict__ out) {
    __shared__ float s_ent[KK];
    __shared__ int   s_used[KK];
    __shared__ float s_com[KK];
    const int k = threadIdx.x;
    const float c = ws[CNT_OFF + k];
    const float p = c * (1.0f / (float)NN);
    s_ent[k]  = p * logf(p + 1e-12f);
    s_used[k] = (p > 0.0f) ? 1 : 0;
    float cs = ws[CPART_OFF + k] + ws[CPART_OFF + 512 + k]
             + ws[CPART_OFF + 1024 + k] + ws[CPART_OFF + 1536 + k];
    s_com[k] = cs;
    __syncthreads();
    for (int off = 256; off > 0; off >>= 1) {
        if (k < off) {
            s_ent[k]  += s_ent[k + off];
            s_used[k] += s_used[k + off];
            s_com[k]  += s_com[k + off];
        }
        __syncthreads();
    }
    if (k == 0) {
        out[COMMIT_OFF] = 0.25f * (s_com[0] + ws[CDELTA_OFF]) / (float)ZQ_SIZE;
        out[PPL_OFF]    = expf(-s_ent[0]);
        out[USE_OFF]    = (float)s_used[0] / (float)KK;
    }
}

extern "C" void kernel_launch(void* const* d_in, const int* in_sizes, int n_in,
                              void* d_out, int out_size, void* d_ws, size_t ws_size,
                              hipStream_t stream) {
    const float* z_e = (const float*)d_in[0];
    const float* emb = (const float*)d_in[1];
    float* out = (float*)d_out;
    float* ws  = (float*)d_ws;

    float* out_idx = out + IDX_OFF;

    vq_init<<<32, 256, 0, stream>>>(emb, ws);
    vq_screen<<<512, 256, 0, stream>>>(z_e, emb, ws, out, out_idx);
    vq_rescue<<<256, 512, 0, stream>>>(z_e, emb, ws, out, out_idx);
    vq_stats<<<1, 512, 0, stream>>>(ws, out);
}